// Round 1
// baseline (1083.068 us; speedup 1.0000x reference)
//
#include <hip/hip_runtime.h>

// Shapes (fixed by the reference): B=32, N_INP=1024, D_INP=1024, N_OUT=64, D_OUT=1024
#define NB   32
#define NI   1024
#define DI   1024
#define NJ   64
#define DO_  1024
#define LDT  68   // padded LDS row stride for GEMM tiles (68*4B = 272B, 16B-aligned)

// ---------------- K0: zero x_out0 (ws) and d_out ----------------
__global__ void k_zero(float4* __restrict__ a, float4* __restrict__ b) {
  int i = blockIdx.x * blockDim.x + threadIdx.x;   // 524288 float4 each
  float4 z = make_float4(0.f, 0.f, 0.f, 0.f);
  a[i] = z;
  b[i] = z;
}

// ---------------- K1: f_a[b][i] = sigmoid(x[b,i,:]·W_A + b_A) ----------------
// one wave per (b,i) row; 4 rows per 256-thread block
__global__ __launch_bounds__(256) void k_gate(const float* __restrict__ x,
                                              const float* __restrict__ W_A,
                                              const float* __restrict__ b_A,
                                              float* __restrict__ f_a) {
  int row  = blockIdx.x * 4 + (threadIdx.x >> 6);   // flat b*NI + i
  int lane = threadIdx.x & 63;
  const float4* xr = (const float4*)(x + (size_t)row * DI);
  const float4* wr = (const float4*)W_A;
  float s = 0.f;
#pragma unroll
  for (int q = 0; q < 4; ++q) {
    float4 v = xr[lane + q * 64];
    float4 w = wr[lane + q * 64];
    s += v.x * w.x + v.y * w.y + v.z * w.z + v.w * w.w;
  }
#pragma unroll
  for (int off = 32; off; off >>= 1) s += __shfl_xor(s, off);
  if (lane == 0) f_a[row] = 1.f / (1.f + __expf(-(s + b_A[0])));
}

// ---------------- K1b: c_T[j][i] = (bu+bi)/64 - bi  (iter-0 phi coefficient) ----------------
__global__ void k_prep_c(const float* __restrict__ bu, const float* __restrict__ bi,
                         float* __restrict__ c_T) {
  int idx = blockIdx.x * 256 + threadIdx.x;   // 65536 = NI*NJ, coalesced over [i][j]
  int i = idx >> 6, j = idx & 63;
  float u = bu[idx], g = bi[idx];
  c_T[j * NI + i] = (u + g) * (1.f / 64.f) - g;
}

// ---------------- K2/K5: x_out[b,j,h] (+)= sum_i phi[b,i,j] * W_mem[i,j,h] ----------------
// grid: (j=64, h-tile=4, i-chunk=4); block 256 threads, one h per thread.
// phi staged in LDS as [b][ii] (64-i chunks); broadcast float4 reads; 32 accumulators.
// ITER==0: phi = f_a[b,i] * c_T[j,i]   ITER==1: phi = phi_T[j][b][i]
template <int ITER>
__global__ __launch_bounds__(256) void k_route(const float* __restrict__ Wm,
                                               const float* __restrict__ f_a,
                                               const float* __restrict__ c_T,
                                               const float* __restrict__ phi_T,
                                               float* __restrict__ out) {
  const int j   = blockIdx.x;         // 0..63
  const int h   = blockIdx.y * 256 + threadIdx.x;
  const int i0  = blockIdx.z * 256;   // 256-i range per block
  const int tid = threadIdx.x;
  __shared__ __align__(16) float phi_s[32][64];   // [b][ii]
  float acc[32];
#pragma unroll
  for (int b = 0; b < 32; ++b) acc[b] = 0.f;

  for (int ch = 0; ch < 4; ++ch) {
    const int ib = i0 + ch * 64;
    __syncthreads();   // protect phi_s from previous chunk's readers
#pragma unroll
    for (int t = tid; t < 32 * 64; t += 256) {
      int b = t >> 6, ii = t & 63;   // ii fastest -> coalesced global reads
      float v;
      if (ITER == 0)
        v = f_a[b * NI + ib + ii] * c_T[j * NI + ib + ii];
      else
        v = phi_T[(size_t)j * (NB * NI) + b * NI + ib + ii];
      phi_s[b][ii] = v;
    }
    __syncthreads();
#pragma unroll
    for (int g = 0; g < 8; ++g) {
      float w[8];
#pragma unroll
      for (int q = 0; q < 8; ++q)
        w[q] = Wm[(size_t)(ib + g * 8 + q) * (NJ * DO_) + j * DO_ + h];
#pragma unroll
      for (int b = 0; b < 32; ++b) {
        const float4 p0 = *(const float4*)&phi_s[b][g * 8];
        const float4 p1 = *(const float4*)&phi_s[b][g * 8 + 4];
        acc[b] += p0.x * w[0] + p0.y * w[1] + p0.z * w[2] + p0.w * w[3] +
                  p1.x * w[4] + p1.y * w[5] + p1.z * w[6] + p1.w * w[7];
      }
    }
  }
#pragma unroll
  for (int b = 0; b < 32; ++b)
    atomicAdd(&out[(size_t)b * (NJ * DO_) + j * DO_ + h], acc[b]);
}

// ---------------- K3: pred[m][d] = x_out0[m][:]·W_G[:,d] + b_G[d], m = b*64+j ----------------
// classic 64x64 tile, 256 threads, 4x4 micro-tile, BK=32
__global__ __launch_bounds__(256) void k_pred(const float* __restrict__ A,   // [2048][1024]
                                              const float* __restrict__ B,   // W_G [1024][1024]
                                              const float* __restrict__ bG,  // [1024]
                                              float* __restrict__ C) {       // pred [2048][1024]
  __shared__ __align__(16) float sm[64][LDT];   // rows 0..31 = As[kk][m], rows 32..63 = Bs[kk][n]
  const int tid = threadIdx.x;
  const int tn = tid & 15, tm = tid >> 4;
  const int m0 = blockIdx.y * 64, n0 = blockIdx.x * 64;
  float acc[4][4] = {};
  for (int k0 = 0; k0 < 1024; k0 += 32) {
    __syncthreads();
#pragma unroll
    for (int it = 0; it < 8; ++it) {
      int idx = tid + it * 256;
      int kk = idx & 31, m = idx >> 5;                      // kk fastest -> coalesced
      sm[kk][m] = A[(size_t)(m0 + m) * 1024 + k0 + kk];     // transposed stage
    }
#pragma unroll
    for (int it = 0; it < 8; ++it) {
      int idx = tid + it * 256;
      int n = idx & 63, kk = idx >> 6;                      // n fastest -> coalesced
      sm[32 + kk][n] = B[(size_t)(k0 + kk) * 1024 + n0 + n];
    }
    __syncthreads();
#pragma unroll
    for (int kk = 0; kk < 32; ++kk) {
      float4 a4 = *(const float4*)&sm[kk][tm * 4];
      float4 b4 = *(const float4*)&sm[32 + kk][tn * 4];
      float av[4] = {a4.x, a4.y, a4.z, a4.w};
      float bv[4] = {b4.x, b4.y, b4.z, b4.w};
#pragma unroll
      for (int p = 0; p < 4; ++p)
#pragma unroll
        for (int q = 0; q < 4; ++q) acc[p][q] += av[p] * bv[q];
    }
  }
#pragma unroll
  for (int p = 0; p < 4; ++p) {
    int m = m0 + tm * 4 + p, nb = n0 + tn * 4;
    float4 o;
    o.x = acc[p][0] + bG[nb + 0];
    o.y = acc[p][1] + bG[nb + 1];
    o.z = acc[p][2] + bG[nb + 2];
    o.w = acc[p][3] + bG[nb + 3];
    *(float4*)&C[(size_t)m * 1024 + nb] = o;
  }
}

// ---------------- K4: S = x·predᵀ/32, softmax over j, phi_T[j][b][i] ----------------
// block = (b, 64-i tile); all 64 j in-block. 4x4 micro-tile, softmax across 16 lanes.
__global__ __launch_bounds__(256) void k_phi(const float* __restrict__ x,     // [32][1024][1024]
                                             const float* __restrict__ pred,  // [2048][1024]
                                             const float* __restrict__ f_a,   // [32][1024]
                                             const float* __restrict__ bu,
                                             const float* __restrict__ bi,
                                             float* __restrict__ phi_T) {     // [64][32][1024]
  __shared__ __align__(16) float sm[64][LDT];
  const int tid = threadIdx.x;
  const int tn = tid & 15, tm = tid >> 4;
  const int b = blockIdx.y;
  const int i0 = blockIdx.x * 64;
  float acc[4][4] = {};
  for (int k0 = 0; k0 < 1024; k0 += 32) {
    __syncthreads();
#pragma unroll
    for (int it = 0; it < 8; ++it) {
      int idx = tid + it * 256;
      int kk = idx & 31, m = idx >> 5;
      sm[kk][m] = x[((size_t)b * NI + i0 + m) * DI + k0 + kk];
    }
#pragma unroll
    for (int it = 0; it < 8; ++it) {
      int idx = tid + it * 256;
      int kk = idx & 31, n = idx >> 5;
      sm[32 + kk][n] = pred[(size_t)(b * 64 + n) * 1024 + k0 + kk];
    }
    __syncthreads();
#pragma unroll
    for (int kk = 0; kk < 32; ++kk) {
      float4 a4 = *(const float4*)&sm[kk][tm * 4];
      float4 b4 = *(const float4*)&sm[32 + kk][tn * 4];
      float av[4] = {a4.x, a4.y, a4.z, a4.w};
      float bv[4] = {b4.x, b4.y, b4.z, b4.w};
#pragma unroll
      for (int p = 0; p < 4; ++p)
#pragma unroll
        for (int q = 0; q < 4; ++q) acc[p][q] += av[p] * bv[q];
    }
  }
  __syncthreads();   // done reading GEMM tiles; smem will be reused for phi staging

  const float sc = 0.03125f;   // 1024^-0.5
#pragma unroll
  for (int p = 0; p < 4; ++p) {
    float v[4];
#pragma unroll
    for (int q = 0; q < 4; ++q) v[q] = acc[p][q] * sc;
    float mx = fmaxf(fmaxf(v[0], v[1]), fmaxf(v[2], v[3]));
#pragma unroll
    for (int off = 1; off < 16; off <<= 1) mx = fmaxf(mx, __shfl_xor(mx, off));
    float e[4], s = 0.f;
#pragma unroll
    for (int q = 0; q < 4; ++q) { e[q] = __expf(v[q] - mx); s += e[q]; }
#pragma unroll
    for (int off = 1; off < 16; off <<= 1) s += __shfl_xor(s, off);
    float inv = 1.f / s;
    int ig = i0 + tm * 4 + p;
    float fa = f_a[b * NI + ig];
#pragma unroll
    for (int q = 0; q < 4; ++q) {
      int j = tn * 4 + q;
      float u = bu[ig * 64 + j], g = bi[ig * 64 + j];
      float R = e[q] * inv;
      sm[j][tm * 4 + p] = fa * (R * (u + g) - g);   // phi tile [j][i_local]
    }
  }
  __syncthreads();
#pragma unroll
  for (int it = 0; it < 16; ++it) {
    int idx = tid + it * 256;   // 4096 = 64j * 64i
    int j = idx >> 6, ii = idx & 63;
    phi_T[(size_t)j * (NB * NI) + (size_t)b * NI + i0 + ii] = sm[j][ii];
  }
}

// ---------------- launch ----------------
extern "C" void kernel_launch(void* const* d_in, const int* in_sizes, int n_in,
                              void* d_out, int out_size, void* d_ws, size_t ws_size,
                              hipStream_t stream) {
  const float* x    = (const float*)d_in[0];   // [32,1024,1024]
  const float* W_A  = (const float*)d_in[1];   // [1024]
  const float* b_A  = (const float*)d_in[2];   // [1]
  const float* Wm   = (const float*)d_in[3];   // [1024,64,1024]
  const float* W_G  = (const float*)d_in[4];   // [1024,1024]
  const float* b_G  = (const float*)d_in[5];   // [1024]
  const float* bu   = (const float*)d_in[6];   // [1024,64]
  const float* bi   = (const float*)d_in[7];   // [1024,64]
  float* out = (float*)d_out;                  // [32,64,1024]

  float* ws     = (float*)d_ws;
  float* f_a    = ws;                     // 32768
  float* c_T    = f_a + 32768;            // 65536
  float* x_out0 = c_T + 65536;            // 2097152
  float* pred   = x_out0 + 2097152;       // 2097152
  float* phi_T  = pred + 2097152;         // 2097152   (total ~24.4 MB)

  // zero x_out0 and d_out (both are atomicAdd targets; ws/d_out are poisoned 0xAA)
  k_zero<<<2048, 256, 0, stream>>>((float4*)x_out0, (float4*)out);

  // gate
  k_gate<<<8192, 256, 0, stream>>>(x, W_A, b_A, f_a);

  // iter-0 phi coefficient
  k_prep_c<<<256, 256, 0, stream>>>(bu, bi, c_T);

  // iter 0: x_out0 = (f_a * c) · W_mem
  k_route<0><<<dim3(64, 4, 4), 256, 0, stream>>>(Wm, f_a, c_T, nullptr, x_out0);

  // pred = x_out0 · W_G + b_G
  k_pred<<<dim3(16, 32), 256, 0, stream>>>(x_out0, W_G, b_G, pred);

  // S = x·predᵀ/32 -> softmax -> phi_T
  k_phi<<<dim3(16, 32), 256, 0, stream>>>(x, pred, f_a, bu, bi, phi_T);

  // iter 1: d_out = phi · W_mem
  k_route<1><<<dim3(64, 4, 4), 256, 0, stream>>>(Wm, f_a, c_T, phi_T, out);
}